// Round 2
// baseline (1364.657 us; speedup 1.0000x reference)
//
#include <hip/hip_runtime.h>

#define NAO   14
#define NOUT  196          // = NAO*NAO, also output width per sample
#define NBLK  56
#define MAXNNZ 26          // max nr*nc = 25
#define TS    64           // samples per workgroup
#define ROWP  200          // padded LDS row (196 -> 200, keeps float4 alignment)

// ---------------- persistent device-side tables (rebuilt every call) --------
__device__ float g_wts[MAXNNZ][NOUT];   // transposed CSR: coalesced in p
__device__ int   g_cols[MAXNNZ][NOUT];
__device__ int   g_nnz[NOUT];

// Block metadata: {L, li, lj, rs, cs, out_off}
// Derived from LS=[0,0,0,1,1,2]; blocks in reference order; out_off from
// stable sort of (L, parity) per INV_PERM.
__constant__ int c_meta[NBLK][6] = {
  {0,0,0, 0,0,  0},{0,0,0, 0,1,  1},{0,0,0, 0,2,  2},{1,0,1, 0,3, 14},{1,0,1, 0,6, 17},{2,0,2, 0,9, 97},
  {0,0,0, 1,0,  3},{0,0,0, 1,1,  4},{0,0,0, 1,2,  5},{1,0,1, 1,3, 20},{1,0,1, 1,6, 23},{2,0,2, 1,9,102},
  {0,0,0, 2,0,  6},{0,0,0, 2,1,  7},{0,0,0, 2,2,  8},{1,0,1, 2,3, 26},{1,0,1, 2,6, 29},{2,0,2, 2,9,107},
  {1,1,0, 3,0, 32},{1,1,0, 3,1, 35},{1,1,0, 3,2, 38},
  {0,1,1, 3,3,  9},{1,1,1, 3,3, 62},{2,1,1, 3,3,112},
  {0,1,1, 3,6, 10},{1,1,1, 3,6, 65},{2,1,1, 3,6,117},
  {1,1,2, 3,9, 41},{2,1,2, 3,9, 77},{3,1,2, 3,9,152},
  {1,1,0, 6,0, 44},{1,1,0, 6,1, 47},{1,1,0, 6,2, 50},
  {0,1,1, 6,3, 11},{1,1,1, 6,3, 68},{2,1,1, 6,3,122},
  {0,1,1, 6,6, 12},{1,1,1, 6,6, 71},{2,1,1, 6,6,127},
  {1,1,2, 6,9, 53},{2,1,2, 6,9, 82},{3,1,2, 6,9,159},
  {2,2,0, 9,0,132},{2,2,0, 9,1,137},{2,2,0, 9,2,142},
  {1,2,1, 9,3, 56},{2,2,1, 9,3, 87},{3,2,1, 9,3,166},
  {1,2,1, 9,6, 59},{2,2,1, 9,6, 92},{3,2,1, 9,6,173},
  {0,2,2, 9,9, 13},{1,2,2, 9,9, 74},{2,2,2, 9,9,147},{3,2,2, 9,9,180},{4,2,2, 9,9,187}
};

// IDX_INV: inverse of IDX_CHANGE = [0,1,2,5,3,4,8,6,7,11,13,9,12,10]
__constant__ int c_idxinv[NAO] = {0,1,2,4,5,3,7,8,6,11,13,9,12,10};

// ---------------- Wigner 3j machinery (fp64, exact mirror of reference) -----
__device__ inline double dfact(int n) {
  double r = 1.0;
  for (int i = 2; i <= n; ++i) r *= (double)i;
  return r;
}
__device__ inline int imin2(int a, int b){ return a < b ? a : b; }
__device__ inline int imax2(int a, int b){ return a > b ? a : b; }

__device__ double su2_cg(int j1,int m1,int j2,int m2,int j3,int m3) {
  if (m3 != m1 + m2) return 0.0;
  int vmin = imax2(imax2(-j1 + j2 + m3, -j1 + m1), 0);
  int vmax = imin2(imin2(j2 + j3 + m1, j3 - j1 + j2), j3 + m3);
  if (vmax < vmin) return 0.0;
  double c = sqrt((double)(2*j3+1) *
                  dfact(j3+j1-j2) * dfact(j3-j1+j2) * dfact(j1+j2-j3) *
                  dfact(j3+m3) * dfact(j3-m3) /
                  (dfact(j1+j2+j3+1) * dfact(j1-m1) * dfact(j1+m1) *
                   dfact(j2-m2) * dfact(j2+m2)));
  double s = 0.0;
  for (int v = vmin; v <= vmax; ++v) {
    double t = dfact(j2+j3+m1-v) * dfact(j1-m1+v) /
               (dfact(v) * dfact(j3-j1+j2-v) * dfact(j3+m3-v) * dfact(v+j1-j2-m3));
    s += (((v + j2 + m2) & 1) ? -1.0 : 1.0) * t;
  }
  return c * s;
}

// q_real_to_complex(l) into row-major (2l+1)x(2l+1) arrays, stride n=2l+1
__device__ void build_q(int l, double* qr, double* qi) {
  int n = 2*l + 1;
  const double is2 = 0.70710678118654752440;
  for (int t = 0; t < n*n; ++t) { qr[t] = 0.0; qi[t] = 0.0; }
  for (int m = -l; m < 0; ++m) {
    qr[(l+m)*n + (l-m)] = is2;    // col l+|m|
    qi[(l+m)*n + (l+m)] = -is2;   // col l-|m|
  }
  qr[l*n + l] = 1.0;
  for (int m = 1; m <= l; ++m) {
    double sgn = (m & 1) ? -1.0 : 1.0;
    qr[(l+m)*n + (l+m)] = sgn * is2;
    qi[(l+m)*n + (l-m)] = sgn * is2;
  }
  // multiply by (-i)^l
  int ph = l & 3;
  if (ph) {
    for (int t = 0; t < n*n; ++t) {
      double a = qr[t], b = qi[t];
      if (ph == 1)      { qr[t] =  b; qi[t] = -a; }   // * (-i)
      else if (ph == 2) { qr[t] = -a; qi[t] = -b; }   // * (-1)
      else              { qr[t] = -b; qi[t] =  a; }   // * (i)
    }
  }
}

// One workgroup (64 threads) per Wigner block: compute cg, normalize, write CSR
__global__ __launch_bounds__(64) void setup_kernel() {
  __shared__ double s_csu2[225];
  __shared__ double s_q1r[81], s_q1i[81];
  __shared__ double s_q2r[25], s_q2i[25];
  __shared__ double s_q3r[25], s_q3i[25];
  __shared__ double s_ccr[225], s_cci[225];
  __shared__ double s_red[128];
  __shared__ double s_sel[2];

  int b   = blockIdx.x;
  int L   = c_meta[b][0], li = c_meta[b][1], lj = c_meta[b][2];
  int rs  = c_meta[b][3], cs = c_meta[b][4], off = c_meta[b][5];
  int n1 = 2*L + 1, n2 = 2*li + 1, n3 = 2*lj + 1;
  int tid = threadIdx.x;
  int ntot = n1 * n2 * n3;

  if (tid == 0) build_q(L,  s_q1r, s_q1i);
  if (tid == 1) build_q(li, s_q2r, s_q2i);
  if (tid == 2) build_q(lj, s_q3r, s_q3i);
  __syncthreads();
  for (int t = tid; t < ntot; t += 64) {
    int i = t / (n2*n3), r = t % (n2*n3);
    int k = r / n3, n = r % n3;
    s_csu2[t] = su2_cg(L, i - L, li, k - li, lj, n - lj);
  }
  __syncthreads();

  double re2 = 0.0, im2 = 0.0;
  for (int t = tid; t < ntot; t += 64) {
    int a = t / (n2*n3), r = t % (n2*n3);
    int bb = r / n3, c = r % n3;
    double accr = 0.0, acci = 0.0;
    for (int i = 0; i < n1; ++i) {
      double ar = s_q1r[i*n1 + a], ai = s_q1i[i*n1 + a];
      for (int k = 0; k < n2; ++k) {
        double br = s_q2r[k*n2 + bb], bi = s_q2i[k*n2 + bb];
        double pr = ar*br - ai*bi;
        double pi = ar*bi + ai*br;
        for (int n = 0; n < n3; ++n) {
          double w = s_csu2[(i*n2 + k)*n3 + n];
          if (w == 0.0) continue;
          double cr = s_q3r[n*n3 + c], ci = -s_q3i[n*n3 + c];  // conj(q3)
          accr += w * (pr*cr - pi*ci);
          acci += w * (pr*ci + pi*cr);
        }
      }
    }
    s_ccr[t] = accr; s_cci[t] = acci;
    re2 += accr*accr; im2 += acci*acci;
  }
  s_red[tid] = re2; s_red[64 + tid] = im2;
  __syncthreads();
  if (tid == 0) {
    double r2 = 0.0, i2 = 0.0;
    for (int t = 0; t < 64; ++t) { r2 += s_red[t]; i2 += s_red[64 + t]; }
    bool pick_re = (sqrt(r2) >= sqrt(i2));
    s_sel[0] = pick_re ? 1.0 : 0.0;
    s_sel[1] = 1.0 / sqrt(pick_re ? r2 : i2);
  }
  __syncthreads();
  bool pick_re = s_sel[0] > 0.5;
  double inv = s_sel[1];

  // thread k (< n1) owns output row off+k; scan (i,j), keep nonzeros
  if (tid < n1) {
    int p = off + tid;
    int q = 0;
    for (int i = 0; i < n2; ++i) {
      int rbase = c_idxinv[rs + i] * NAO;
      for (int j = 0; j < n3; ++j) {
        int t = (tid*n2 + i)*n3 + j;
        double v = (pick_re ? s_ccr[t] : s_cci[t]) * inv;
        if (fabs(v) > 1e-10) {
          g_cols[q][p] = rbase + c_idxinv[cs + j];
          g_wts[q][p]  = (float)v;
          ++q;
        }
      }
    }
    g_nnz[p] = q;
  }
}

// ---------------- main kernel: 64 samples / WG, LDS-staged sparse matvec ----
__global__ __launch_bounds__(256) void expand_kernel(const float* __restrict__ x,
                                                     float* __restrict__ out,
                                                     int total) {
  __shared__ float xs[TS * ROWP];
  int base = blockIdx.x * (TS * NOUT);

  // Phase 1: coalesced float4 tile load -> LDS (196 = 4*49, rows never split)
  for (int t4 = threadIdx.x; t4 < TS * 49; t4 += 256) {
    int g = base + 4 * t4;
    float4 v = make_float4(0.f, 0.f, 0.f, 0.f);
    if (g < total) v = ((const float4*)x)[(base >> 2) + t4];
    int s = t4 / 49, i4 = t4 - s * 49;
    *(float4*)&xs[s * ROWP + i4 * 4] = v;
  }
  __syncthreads();

  // Phase 2: each thread computes 4 consecutive outputs of one sample
  for (int t4 = threadIdx.x; t4 < TS * 49; t4 += 256) {
    int g = base + 4 * t4;
    if (g >= total) break;
    int s = t4 / 49, p0 = (t4 - s * 49) * 4;
    const float* row = &xs[s * ROWP];
    float4 r;
    float* pr = &r.x;
    #pragma unroll
    for (int u = 0; u < 4; ++u) {
      int p = p0 + u;
      int nz = g_nnz[p];
      float acc = 0.f;
      for (int q = 0; q < nz; ++q) {
        acc += g_wts[q][p] * row[g_cols[q][p]];
      }
      pr[u] = acc;
    }
    *(float4*)&out[g] = r;
  }
}

extern "C" void kernel_launch(void* const* d_in, const int* in_sizes, int n_in,
                              void* d_out, int out_size, void* d_ws, size_t ws_size,
                              hipStream_t stream) {
  const float* x = (const float*)d_in[0];
  float* out = (float*)d_out;
  int total = in_sizes[0];              // nsamp * 196 (in and out widths match)
  int nsamp = total / NOUT;
  int nblocks = (nsamp + TS - 1) / TS;

  setup_kernel<<<dim3(NBLK), dim3(64), 0, stream>>>();
  expand_kernel<<<dim3(nblocks), dim3(256), 0, stream>>>(x, out, total);
}